// Round 6
// baseline (147.919 us; speedup 1.0000x reference)
//
#include <hip/hip_runtime.h>
#include <cstdint>

// IDCT (DCT-III) of 4096x4096 fp32 via even/odd decimation + int8 MFMA GEMMs.
//   y_k       = E_k + O_k          (k < N/2)
//   y_{N-1-k} = E_k - O_k
//   E_k = sum_m we_m x[2m]   cos(pi*m*(2k+1)/N)      (we_0=1, else 2)
//   O_k = sum_m 2    x[2m+1] cos(pi*(2m+1)*(2k+1)/(2N))
// R6: mfma_i32_32x32x32_i8 (32x32 shape = +12-17% matrix-pipe efficiency vs
// 16x16, m119/m55) in the R5 fused E/O K-loop (4 tiles, 64 KB LDS, XOR
// swizzle, 0 conflicts). Epilogue now writes 128 B contiguous per store.

#define NN 4096
#define HH 2048   // N/2 = K-dim of the split GEMMs and half-spectrum width
#define BM 128
#define BN 128
#define BK 128    // i8 elems per K-step (128 B rows -> proven swizzle geometry)

typedef int i32x4  __attribute__((ext_vector_type(4)));
typedef int i32x2  __attribute__((ext_vector_type(2)));
typedef int i32x16 __attribute__((ext_vector_type(16)));

// async global->LDS, 16B per lane (HW: LDS dest = wave-uniform base + lane*16)
__device__ __forceinline__ void async_copy16(void* lds_base, const void* gptr) {
    __builtin_amdgcn_global_load_lds(
        (const __attribute__((address_space(1))) unsigned int*)gptr,
        (__attribute__((address_space(3))) unsigned int*)lds_base,
        16, 0, 0);
}

__device__ __forceinline__ int pack4(int q0, int q1, int q2, int q3) {
    return (q0 & 255) | ((q1 & 255) << 8) | ((q2 & 255) << 16) | ((q3 & 255) << 24);
}

// ---- prep ----
// blocks 0..4095     : quantize row b of X into Ae (even cols) + Ao (odd cols),
//                      per-row-per-parity scales se[b], so[b]
// blocks 4096..6143  : CE row k  (CE[k][m] = we_m cos(pi*m*(2k+1)/N))
// blocks 6144..8191  : CO row k  (CO[k][m] = 2 cos(pi*(2m+1)*(2k+1)/2N))
__global__ __launch_bounds__(256) void prep_i8(const float* __restrict__ x,
                                               signed char* __restrict__ Ae,
                                               signed char* __restrict__ Ao,
                                               signed char* __restrict__ CEm,
                                               signed char* __restrict__ COm,
                                               float* __restrict__ se,
                                               float* __restrict__ so) {
    const int b = blockIdx.x;
    const int t = threadIdx.x;
    const float s = 3.834951969714103e-4f;   // pi / 8192

    if (b < 4096) {
        __shared__ float wmaxe[4], wmaxo[4];
        const float* xr = x + (size_t)b * NN;
        float v[16];                          // elements n = t*16 .. t*16+15
#pragma unroll
        for (int j = 0; j < 4; ++j) {
            float4 f = ((const float4*)xr)[t * 4 + j];
            v[j * 4 + 0] = f.x; v[j * 4 + 1] = f.y;
            v[j * 4 + 2] = f.z; v[j * 4 + 3] = f.w;
        }
        float emax = 1e-30f, omax = 1e-30f;
#pragma unroll
        for (int i = 0; i < 8; ++i) {
            emax = fmaxf(emax, __builtin_fabsf(v[2 * i]));
            omax = fmaxf(omax, __builtin_fabsf(v[2 * i + 1]));
        }
        // 64-lane butterfly reduce (no barrier)
#pragma unroll
        for (int m = 1; m < 64; m <<= 1) {
            emax = fmaxf(emax, __shfl_xor(emax, m));
            omax = fmaxf(omax, __shfl_xor(omax, m));
        }
        const int wv = t >> 6;
        if ((t & 63) == 0) { wmaxe[wv] = emax; wmaxo[wv] = omax; }
        __syncthreads();
        const float rmax_e = fmaxf(fmaxf(wmaxe[0], wmaxe[1]), fmaxf(wmaxe[2], wmaxe[3]));
        const float rmax_o = fmaxf(fmaxf(wmaxo[0], wmaxo[1]), fmaxf(wmaxo[2], wmaxo[3]));
        const float inv_e = 127.0f / rmax_e, inv_o = 127.0f / rmax_o;
        int qe[8], qo[8];
#pragma unroll
        for (int i = 0; i < 8; ++i) {
            qe[i] = (int)rintf(v[2 * i] * inv_e);
            qo[i] = (int)rintf(v[2 * i + 1] * inv_o);
        }
        i32x2 oe, oo;
        oe[0] = pack4(qe[0], qe[1], qe[2], qe[3]);
        oe[1] = pack4(qe[4], qe[5], qe[6], qe[7]);
        oo[0] = pack4(qo[0], qo[1], qo[2], qo[3]);
        oo[1] = pack4(qo[4], qo[5], qo[6], qo[7]);
        ((i32x2*)(Ae + (size_t)b * HH))[t] = oe;   // m = t*8 .. t*8+7
        ((i32x2*)(Ao + (size_t)b * HH))[t] = oo;
        if (t == 0) {
            se[b] = rmax_e * (1.0f / 127.0f);
            so[b] = rmax_o * (1.0f / 127.0f);
        }
    } else if (b < 6144) {
        const int k = b - 4096;
        const int twok1 = 2 * k + 1;
        int q[8];
#pragma unroll
        for (int i = 0; i < 8; ++i) {
            int m = t * 8 + i;
            int p = (2 * m * twok1) & 16383;            // angle = p * pi/8192
            float w = (m == 0) ? 1.0f : 2.0f;
            q[i] = (int)rintf(w * __cosf((float)p * s) * 63.5f);  // scale 2/127
        }
        i32x2 o;
        o[0] = pack4(q[0], q[1], q[2], q[3]);
        o[1] = pack4(q[4], q[5], q[6], q[7]);
        ((i32x2*)(CEm + (size_t)k * HH))[t] = o;
    } else {
        const int k = b - 6144;
        const int twok1 = 2 * k + 1;
        int q[8];
#pragma unroll
        for (int i = 0; i < 8; ++i) {
            int m = t * 8 + i;
            int p = ((2 * m + 1) * twok1) & 16383;
            q[i] = (int)rintf(__cosf((float)p * s) * 127.0f);     // 2*cos, scale 2/127
        }
        i32x2 o;
        o[0] = pack4(q[0], q[1], q[2], q[3]);
        o[1] = pack4(q[4], q[5], q[6], q[7]);
        ((i32x2*)(COm + (size_t)k * HH))[t] = o;
    }
}

// ---- fused split GEMM: accE = Ae*CE^T and accO = Ao*CO^T in one K-loop ----
// 128x128 tile, BK=128, 4 waves 2x2, each wave 2x2 grid of 32x32x32 MFMA per
// branch. XOR-swizzled LDS (granule g of row r at g^(r&7)) -> 0 conflicts.
__global__ __launch_bounds__(256, 2) void idct_gemm2(const signed char* __restrict__ Ae,
                                                     const signed char* __restrict__ Ao,
                                                     const signed char* __restrict__ CEm,
                                                     const signed char* __restrict__ COm,
                                                     const float* __restrict__ se,
                                                     const float* __restrict__ so,
                                                     float* __restrict__ C) {
    __shared__ __align__(16) signed char sAe[BM * BK];   // 16 KB
    __shared__ __align__(16) signed char sAo[BM * BK];   // 16 KB
    __shared__ __align__(16) signed char sCE[BN * BK];   // 16 KB
    __shared__ __align__(16) signed char sCO[BN * BK];   // 16 KB  (total 64 KB)

    const int tid  = threadIdx.x;
    const int wave = tid >> 6;
    const int lane = tid & 63;
    const int waveM = wave >> 1;
    const int waveN = wave & 1;

    const int rowBase = blockIdx.y * BM;        // output rows
    const int colBase = blockIdx.x * BN;        // half-spectrum cols k in [0,2048)

    i32x16 accE[2][2] = {};
    i32x16 accO[2][2] = {};

    // staging: chunk = 1 KB = 8 rows x 8 granules(16B); 16 chunks per matrix
    const int srow  = lane >> 3;              // row within chunk (== r&7)
    const int sgran = lane & 7;               // physical granule this lane fills
    const int ggcol = (sgran ^ srow) * 16;    // swizzle baked into global col (bytes)
    const int rmod  = lane & 7;               // r&7 for fragment rows (r = lane&31)
    const int halfk = lane >> 5;              // K-half within the 32-wide k-step

    for (int k0 = 0; k0 < HH; k0 += BK) {
#pragma unroll
        for (int j = 0; j < 4; ++j) {
            int ck = wave * 4 + j;                // chunk 0..15 (8 rows each)
            int r  = ck * 8 + srow;               // 0..127
            size_t aoff = (size_t)(rowBase + r) * HH + k0 + ggcol;
            size_t boff = (size_t)(colBase + r) * HH + k0 + ggcol;
            async_copy16(&sAe[ck * 1024], Ae + aoff);
            async_copy16(&sAo[ck * 1024], Ao + aoff);
            async_copy16(&sCE[ck * 1024], CEm + boff);
            async_copy16(&sCO[ck * 1024], COm + boff);
        }
        __syncthreads();

#pragma unroll
        for (int kk = 0; kk < 4; ++kk) {
            // A-frag k = (lane>>5)*16 + j -> logical granule g = kk*2 + halfk;
            // physical p = g ^ (r&7)
            const int poff = ((kk * 2 + halfk) ^ rmod) * 16;   // bytes
            {
                i32x4 af[2], bfr[2];
#pragma unroll
                for (int mi = 0; mi < 2; ++mi) {
                    int r = waveM * 64 + mi * 32 + (lane & 31);
                    af[mi] = *(const i32x4*)&sAe[r * BK + poff];
                }
#pragma unroll
                for (int ni = 0; ni < 2; ++ni) {
                    int r = waveN * 64 + ni * 32 + (lane & 31);
                    bfr[ni] = *(const i32x4*)&sCE[r * BK + poff];
                }
#pragma unroll
                for (int mi = 0; mi < 2; ++mi)
#pragma unroll
                    for (int ni = 0; ni < 2; ++ni)
                        accE[mi][ni] = __builtin_amdgcn_mfma_i32_32x32x32_i8(
                            af[mi], bfr[ni], accE[mi][ni], 0, 0, 0);
            }
            {
                i32x4 af[2], bfr[2];
#pragma unroll
                for (int mi = 0; mi < 2; ++mi) {
                    int r = waveM * 64 + mi * 32 + (lane & 31);
                    af[mi] = *(const i32x4*)&sAo[r * BK + poff];
                }
#pragma unroll
                for (int ni = 0; ni < 2; ++ni) {
                    int r = waveN * 64 + ni * 32 + (lane & 31);
                    bfr[ni] = *(const i32x4*)&sCO[r * BK + poff];
                }
#pragma unroll
                for (int mi = 0; mi < 2; ++mi)
#pragma unroll
                    for (int ni = 0; ni < 2; ++ni)
                        accO[mi][ni] = __builtin_amdgcn_mfma_i32_32x32x32_i8(
                            af[mi], bfr[ni], accO[mi][ni], 0, 0, 0);
            }
        }
        __syncthreads();
    }

    // epilogue: 32x32 C/D layout col = lane&31, row = (reg&3)+8*(reg>>2)+4*(lane>>5)
    // (m74/m101-verified, dtype-independent). Butterfly into cc and NN-1-cc.
    const float sB_s = 2.0f / 127.0f;
#pragma unroll
    for (int mi = 0; mi < 2; ++mi)
#pragma unroll
        for (int ni = 0; ni < 2; ++ni)
#pragma unroll
            for (int rg = 0; rg < 16; ++rg) {
                int rr = rowBase + waveM * 64 + mi * 32
                       + (rg & 3) + 8 * (rg >> 2) + 4 * halfk;
                int cc = colBase + waveN * 64 + ni * 32 + (lane & 31);
                float e = (float)accE[mi][ni][rg] * (se[rr] * sB_s);
                float o = (float)accO[mi][ni][rg] * (so[rr] * sB_s);
                C[(size_t)rr * NN + cc] = e + o;
                C[(size_t)rr * NN + (NN - 1 - cc)] = e - o;
            }
}

// ---- fallback: direct O(N^2) eval (only if ws_size is too small) ----
__global__ __launch_bounds__(256) void idct_naive(const float* __restrict__ x,
                                                  float* __restrict__ out) {
    int row = blockIdx.x;
    __shared__ float sx[NN];
    for (int i = threadIdx.x; i < NN; i += 256) sx[i] = x[(size_t)row * NN + i];
    __syncthreads();
    const float s = 3.834951969714103e-4f;  // pi / 8192
    for (int k = threadIdx.x; k < NN; k += 256) {
        int twok1 = 2 * k + 1;
        float acc = sx[0];
        int p = 0;
        for (int n = 1; n < NN; ++n) {
            p += twok1; p &= 16383;
            acc += 2.0f * sx[n] * __cosf((float)p * s);
        }
        out[(size_t)row * NN + k] = acc;
    }
}

extern "C" void kernel_launch(void* const* d_in, const int* in_sizes, int n_in,
                              void* d_out, int out_size, void* d_ws, size_t ws_size,
                              hipStream_t stream) {
    const float* x = (const float*)d_in[0];
    float* out = (float*)d_out;

    const size_t eA = (size_t)NN * HH;          // 8 MB each for Ae/Ao
    const size_t eC = (size_t)HH * HH;          // 4 MB each for CE/CO
    const size_t need = 2 * eA + 2 * eC + 2 * NN * sizeof(float);

    if (ws_size >= need) {
        signed char* Ae = (signed char*)d_ws;
        signed char* Ao = Ae + eA;
        signed char* CEm = Ao + eA;
        signed char* COm = CEm + eC;
        float* se = (float*)(COm + eC);
        float* so = se + NN;

        prep_i8<<<8192, 256, 0, stream>>>(x, Ae, Ao, CEm, COm, se, so);

        dim3 grid(HH / BN, NN / BM);            // (16, 32) = 512 blocks
        idct_gemm2<<<grid, 256, 0, stream>>>(Ae, Ao, CEm, COm, se, so, out);
    } else {
        idct_naive<<<NN, 256, 0, stream>>>(x, out);
    }
}